// Round 1
// baseline (375.841 us; speedup 1.0000x reference)
//
#include <hip/hip_runtime.h>

#define NB 16
#define NEV 960000
#define NS 48
#define SEG 20000
#define S_IDX 3
#define E_IDX 38
#define N_ITER 34
#define ND 256
#define OUT_WIN 10

// ---------------- Kernel 1: per-(batch,chunk) x/y histograms ----------------
__global__ __launch_bounds__(256) void hist_kernel(const float* __restrict__ events,
                                                   float* __restrict__ alongX,
                                                   float* __restrict__ alongY) {
    __shared__ unsigned hx[ND], hy[ND];
    int tid = threadIdx.x;
    int blk = blockIdx.x;
    int b = blk / NS, c = blk % NS;
    hx[tid] = 0; hy[tid] = 0;
    __syncthreads();
    size_t base = (size_t)b * NEV + (size_t)c * SEG;
    const float4* ev4 = (const float4*)(events + base * 2);   // 2 events per float4
    for (int k = tid; k < SEG / 2; k += 256) {
        float4 v = ev4[k];
        int x0 = (int)v.x, y0 = (int)v.y, x1 = (int)v.z, y1 = (int)v.w;
        x0 = x0 > 255 ? 255 : x0; y0 = y0 > 255 ? 255 : y0;
        x1 = x1 > 255 ? 255 : x1; y1 = y1 > 255 ? 255 : y1;
        atomicAdd(&hx[x0], 1u); atomicAdd(&hy[y0], 1u);
        atomicAdd(&hx[x1], 1u); atomicAdd(&hy[y1], 1u);
    }
    __syncthreads();
    int o = (b * NS + c) * ND + tid;
    alongX[o] = (float)hx[tid];
    alongY[o] = (float)hy[tid];
}

// ---------------- Kernel 2: cv, blur-centroid m, aligned, outlier flags ----
__device__ inline double blk_reduce256(double v, double* sred, int tid) {
    for (int off = 32; off; off >>= 1) v += __shfl_down(v, off);
    if ((tid & 63) == 0) sred[tid >> 6] = v;
    __syncthreads();
    double r = sred[0] + sred[1] + sred[2] + sred[3];
    __syncthreads();
    return r;
}

__device__ inline float median10(const float* v) {
    float w[10];
    #pragma unroll
    for (int i = 0; i < 10; i++) w[i] = v[i];
    #pragma unroll
    for (int i = 1; i < 10; i++) {
        float k = w[i]; int j = i - 1;
        while (j >= 0 && w[j] > k) { w[j + 1] = w[j]; j--; }
        w[j + 1] = k;
    }
    return 0.5f * (w[4] + w[5]);
}

__device__ inline bool outlier_flag(const float* w) {
    float med = median10(w);
    float d[10];
    #pragma unroll
    for (int i = 0; i < 10; i++) d[i] = fabsf(w[i] - med);
    float d0 = d[0];
    float mad = median10(d);
    return (0.6745f * d0 / mad) > 2.0f;
}

__global__ __launch_bounds__(256) void stats_kernel(const float* __restrict__ alongX,
                                                    const float* __restrict__ alongY,
                                                    int* __restrict__ alignedX,
                                                    int* __restrict__ alignedY,
                                                    int* __restrict__ is_out) {
    __shared__ float sbuf[NS * ND];        // 48 KB
    __shared__ double sred[4];
    __shared__ float sm[2][NS];
    __shared__ int sal[2][NS];
    __shared__ float scv;
    int tid = threadIdx.x, b = blockIdx.x;

    for (int axis = 0; axis < 2; ++axis) {
        const float* along = (axis ? alongY : alongX) + (size_t)b * NS * ND;
        for (int k = 0; k < NS; k++) sbuf[k * ND + tid] = along[k * ND + tid];
        __syncthreads();
        // cv = mean + 3*std(ddof=1) over all 48*256 raw counts
        double s = 0.0, s2 = 0.0;
        for (int k = 0; k < NS; k++) { double v = sbuf[k * ND + tid]; s += v; s2 += v * v; }
        double ts  = blk_reduce256(s,  sred, tid);
        double ts2 = blk_reduce256(s2, sred, tid);
        if (tid == 0) {
            const double N = (double)(NS * ND);
            double mean = ts / N;
            double var  = (ts2 - ts * ts / N) / (N - 1.0);
            scv = (float)(mean + 3.0 * sqrt(var));
        }
        __syncthreads();
        float cv = scv;
        // W(d) = sum of indices in [d-2,d+2] ∩ [0,255]
        int lo = tid - 2 < 0 ? 0 : tid - 2;
        int hi = tid + 2 > 255 ? 255 : tid + 2;
        double Wd = 0.5 * (double)(lo + hi) * (double)(hi - lo + 1);
        for (int sI = 0; sI < NS; sI++) {
            double t = 0.0;
            #pragma unroll
            for (int ds = -2; ds <= 2; ++ds) {
                int ss = sI + ds;
                if (ss >= 0 && ss < NS) t += (double)fminf(sbuf[ss * ND + tid], cv);
            }
            double tot = blk_reduce256(t * Wd, sred, tid);
            if (tid == 0) {
                double m = tot * 0.04 / (double)SEG;
                float mf = (float)m;
                sm[axis][sI] = mf;
                sal[axis][sI] = (int)rintf(mf - 128.0f);   // m - start - (128 - start) == m - 128
            }
        }
        __syncthreads();
    }
    if (tid < NS) {
        alignedX[b * NS + tid] = sal[0][tid];
        alignedY[b * NS + tid] = sal[1][tid];
    }
    if (tid < N_ITER) {
        bool f = outlier_flag(&sm[0][S_IDX + 1 + tid]) || outlier_flag(&sm[1][S_IDX + 1 + tid]);
        is_out[b * N_ITER + tid] = f ? 1 : 0;
    }
}

// ---------------- Kernel 3: sequential per-batch scan ----------------------
__global__ __launch_bounds__(1024) void scan_kernel(const float* __restrict__ events,
                                                    const int* __restrict__ alignedX,
                                                    const int* __restrict__ alignedY,
                                                    const int* __restrict__ is_out,
                                                    unsigned* __restrict__ container) {
    __shared__ unsigned ver[512], delta[512];   // 16384-bit masks
    __shared__ int s_ax[NS], s_ay[NS], s_o[N_ITER];
    __shared__ unsigned s_cnt, s_ni;
    __shared__ int s_do, s_stop;
    int tid = threadIdx.x, b = blockIdx.x;
    if (tid < 512) ver[tid] = 0;
    if (tid < NS) { s_ax[tid] = alignedX[b * NS + tid]; s_ay[tid] = alignedY[b * NS + tid]; }
    if (tid < N_ITER) s_o[tid] = is_out[b * N_ITER + tid];
    if (tid == 0) { s_cnt = 0; s_stop = 0; s_do = 0; }
    __syncthreads();
    unsigned* cont = container + (size_t)b * 65536;
    const float* evb = events + (size_t)b * NEV * 2;

    // chunk S_IDX: unconditional commit
    {
        int aX = s_ax[S_IDX], aY = s_ay[S_IDX];
        const float2* ev = (const float2*)(evb + (size_t)S_IDX * SEG * 2);
        for (int i = tid; i < SEG; i += 1024) {
            float2 e = ev[i];
            int xs = (int)e.x - aX; xs = xs < 0 ? 0 : (xs > 255 ? 255 : xs);
            int ys = (int)e.y - aY; ys = ys < 0 ? 0 : (ys > 255 ? 255 : ys);
            int iv = (xs >> 1) | ((ys >> 1) << 7);
            unsigned bit = 1u << (iv & 31);
            unsigned old = atomicOr(&ver[iv >> 5], bit);
            if (!(old & bit)) atomicAdd(&s_cnt, 1u);
            atomicAdd(&cont[xs | (ys << 8)], 1u);
        }
    }
    __syncthreads();

    for (int si = S_IDX + 1; si < E_IDX; ++si) {
        if (s_stop) break;
        if (s_o[si - (S_IDX + 1)]) continue;     // outlier: skip, no stop
        if (tid < 512) delta[tid] = 0;
        if (tid == 0) s_ni = 0;
        __syncthreads();
        int aX = s_ax[si], aY = s_ay[si];
        const float2* ev = (const float2*)(evb + (size_t)si * SEG * 2);
        // pass 1: new-info count via delta mask (no commit)
        for (int i = tid; i < SEG; i += 1024) {
            float2 e = ev[i];
            int xs = (int)e.x - aX; xs = xs < 0 ? 0 : (xs > 255 ? 255 : xs);
            int ys = (int)e.y - aY; ys = ys < 0 ? 0 : (ys > 255 ? 255 : ys);
            int iv = (xs >> 1) | ((ys >> 1) << 7);
            unsigned w = iv >> 5, bit = 1u << (iv & 31);
            if (!(ver[w] & bit)) {
                unsigned old = atomicOr(&delta[w], bit);
                if (!(old & bit)) atomicAdd(&s_ni, 1u);
            }
        }
        __syncthreads();
        if (tid == 0) {
            unsigned ni = s_ni, cn = s_cnt + ni;
            float ratio = (float)ni / (float)cn;   // f32 div of exact ints — matches jax
            if (ratio < 0.1f) { s_stop = 1; s_do = 0; }
            else { s_do = 1; s_cnt = cn; }
        }
        __syncthreads();
        if (s_do) {
            // pass 2: commit container + ver
            for (int i = tid; i < SEG; i += 1024) {
                float2 e = ev[i];
                int xs = (int)e.x - aX; xs = xs < 0 ? 0 : (xs > 255 ? 255 : xs);
                int ys = (int)e.y - aY; ys = ys < 0 ? 0 : (ys > 255 ? 255 : ys);
                atomicAdd(&cont[xs | (ys << 8)], 1u);
            }
            if (tid < 512) ver[tid] |= delta[tid];
        }
        __syncthreads();
    }
}

// ---------------- Kernel 4: per-batch normalize ----------------------------
__global__ __launch_bounds__(1024) void norm_kernel(const unsigned* __restrict__ container,
                                                    float* __restrict__ out) {
    __shared__ double sredA[16], sredB[16];
    __shared__ float scv;
    int tid = threadIdx.x, b = blockIdx.x;
    const unsigned* cont = container + (size_t)b * 65536;
    double s = 0.0, s2 = 0.0;
    for (int i = tid; i < 65536; i += 1024) {
        double v = (double)cont[i];
        s += v; s2 += v * v;
    }
    for (int off = 32; off; off >>= 1) { s += __shfl_down(s, off); s2 += __shfl_down(s2, off); }
    if ((tid & 63) == 0) { sredA[tid >> 6] = s; sredB[tid >> 6] = s2; }
    __syncthreads();
    if (tid == 0) {
        double ts = 0.0, ts2 = 0.0;
        for (int i = 0; i < 16; i++) { ts += sredA[i]; ts2 += sredB[i]; }
        double mean = ts / 65536.0;
        double var = (ts2 - ts * ts / 65536.0) / 65535.0;
        scv = (float)(mean + 3.0 * sqrt(var));
    }
    __syncthreads();
    float cv = scv;
    float* ob = out + (size_t)b * 65536;
    for (int i = tid; i < 65536; i += 1024) {
        float c = (float)cont[i];
        ob[i] = fminf(c, cv) / cv;
    }
}

// ---------------- Launcher -------------------------------------------------
extern "C" void kernel_launch(void* const* d_in, const int* in_sizes, int n_in,
                              void* d_out, int out_size, void* d_ws, size_t ws_size,
                              hipStream_t stream) {
    const float* events = (const float*)d_in[0];
    float* out = (float*)d_out;
    char* ws = (char*)d_ws;

    // workspace layout (bytes):
    //   alongX   [16*48*256 f32]  @ 0         (786432)
    //   alongY   [16*48*256 f32]  @ 786432    (786432)
    //   container[16*65536 u32]   @ 1572864   (4194304)
    //   alignedX [16*48 i32]      @ 5767168   (3072)
    //   alignedY [16*48 i32]      @ 5770240   (3072)
    //   is_out   [16*34 i32]      @ 5773312   (2176)
    float*    alongX    = (float*)(ws);
    float*    alongY    = (float*)(ws + 786432);
    unsigned* container = (unsigned*)(ws + 1572864);
    int*      alignedX  = (int*)(ws + 5767168);
    int*      alignedY  = (int*)(ws + 5770240);
    int*      is_out    = (int*)(ws + 5773312);

    hipMemsetAsync(container, 0, (size_t)NB * 65536 * sizeof(unsigned), stream);
    hist_kernel<<<NB * NS, 256, 0, stream>>>(events, alongX, alongY);
    stats_kernel<<<NB, 256, 0, stream>>>(alongX, alongY, alignedX, alignedY, is_out);
    scan_kernel<<<NB, 1024, 0, stream>>>(events, alignedX, alignedY, is_out, container);
    norm_kernel<<<NB, 1024, 0, stream>>>(container, out);
}

// Round 2
// 307.241 us; speedup vs baseline: 1.2233x; 1.2233x over previous
//
#include <hip/hip_runtime.h>

#define NB 16
#define NEV 960000
#define NS 48
#define SEG 20000
#define S_IDX 3
#define E_IDX 38
#define N_ITER 34
#define ND 256
#define NCH 35          // chunks S_IDX .. E_IDX-1

// ---------------- Kernel 1: per-(batch,chunk) x/y histograms ----------------
__global__ __launch_bounds__(256) void hist_kernel(const float* __restrict__ events,
                                                   float* __restrict__ alongX,
                                                   float* __restrict__ alongY) {
    __shared__ unsigned hx[ND], hy[ND];
    int tid = threadIdx.x;
    int blk = blockIdx.x;
    int b = blk / NS, c = blk % NS;
    hx[tid] = 0; hy[tid] = 0;
    __syncthreads();
    size_t base = (size_t)b * NEV + (size_t)c * SEG;
    const float4* ev4 = (const float4*)(events + base * 2);   // 2 events per float4
    for (int k = tid; k < SEG / 2; k += 256) {
        float4 v = ev4[k];
        int x0 = (int)v.x, y0 = (int)v.y, x1 = (int)v.z, y1 = (int)v.w;
        x0 = x0 > 255 ? 255 : x0; y0 = y0 > 255 ? 255 : y0;
        x1 = x1 > 255 ? 255 : x1; y1 = y1 > 255 ? 255 : y1;
        atomicAdd(&hx[x0], 1u); atomicAdd(&hy[y0], 1u);
        atomicAdd(&hx[x1], 1u); atomicAdd(&hy[y1], 1u);
    }
    __syncthreads();
    int o = (b * NS + c) * ND + tid;
    alongX[o] = (float)hx[tid];
    alongY[o] = (float)hy[tid];
}

// ---------------- Kernel 2: cv, blur-centroid m, aligned -------------------
// One block per (batch, axis); 4 waves x 12 segments, wave-local reductions.
__global__ __launch_bounds__(256) void stats_kernel(const float* __restrict__ alongX,
                                                    const float* __restrict__ alongY,
                                                    int* __restrict__ alignedX,
                                                    int* __restrict__ alignedY,
                                                    float* __restrict__ m_all) {
    __shared__ float sbuf[NS * ND];        // 48 KB
    __shared__ double sredA[4], sredB[4];
    __shared__ float scv;
    int tid = threadIdx.x;
    int b = blockIdx.x >> 1, axis = blockIdx.x & 1;
    const float* along = (axis ? alongY : alongX) + (size_t)b * NS * ND;
    for (int k = 0; k < NS; k++) sbuf[k * ND + tid] = along[k * ND + tid];
    __syncthreads();
    // cv = mean + 3*std(ddof=1) over all 48*256 raw counts
    double s = 0.0, s2 = 0.0;
    for (int k = 0; k < NS; k++) { double v = sbuf[k * ND + tid]; s += v; s2 += v * v; }
    for (int off = 32; off; off >>= 1) { s += __shfl_down(s, off); s2 += __shfl_down(s2, off); }
    if ((tid & 63) == 0) { sredA[tid >> 6] = s; sredB[tid >> 6] = s2; }
    __syncthreads();
    if (tid == 0) {
        double ts = sredA[0] + sredA[1] + sredA[2] + sredA[3];
        double ts2 = sredB[0] + sredB[1] + sredB[2] + sredB[3];
        const double N = (double)(NS * ND);
        double mean = ts / N;
        double var  = (ts2 - ts * ts / N) / (N - 1.0);
        scv = (float)(mean + 3.0 * sqrt(var));
    }
    __syncthreads();
    float cv = scv;
    int wave = tid >> 6, lane = tid & 63;
    // wave w handles segments w*12 .. w*12+11; no block barriers in this loop
    for (int q = 0; q < 12; ++q) {
        int sI = wave * 12 + q;
        double acc = 0.0;
        #pragma unroll
        for (int k = 0; k < 4; ++k) {
            int d = lane + 64 * k;
            int lo = d - 2 < 0 ? 0 : d - 2;
            int hi = d + 2 > 255 ? 255 : d + 2;
            double Wd = 0.5 * (double)(lo + hi) * (double)(hi - lo + 1);
            double t = 0.0;
            #pragma unroll
            for (int ds = -2; ds <= 2; ++ds) {
                int ss = sI + ds;
                if (ss >= 0 && ss < NS) t += (double)fminf(sbuf[ss * ND + d], cv);
            }
            acc += t * Wd;
        }
        for (int off = 32; off; off >>= 1) acc += __shfl_down(acc, off);
        if (lane == 0) {
            float mf = (float)(acc * 0.04 / (double)SEG);
            m_all[(b * 2 + axis) * NS + sI] = mf;
            // m - start - (128 - start) == m - 128 (Sterbenz-exact)
            (axis ? alignedY : alignedX)[b * NS + sI] = (int)rintf(mf - 128.0f);
        }
    }
}

// ---------------- Kernel 3a: per-(batch,chunk) half-res visit masks --------
__global__ __launch_bounds__(256) void mask_kernel(const float* __restrict__ events,
                                                   const int* __restrict__ alignedX,
                                                   const int* __restrict__ alignedY,
                                                   unsigned* __restrict__ masks) {
    __shared__ unsigned sm[512];
    int tid = threadIdx.x, blk = blockIdx.x;
    int b = blk / NCH, ci = blk % NCH, si = S_IDX + ci;
    sm[tid] = 0; sm[tid + 256] = 0;
    __syncthreads();
    int aX = alignedX[b * NS + si], aY = alignedY[b * NS + si];
    const float4* ev = (const float4*)(events + ((size_t)b * NEV + (size_t)si * SEG) * 2);
    for (int i = tid; i < SEG / 2; i += 256) {
        float4 e = ev[i];
        int xs0 = (int)e.x - aX; xs0 = xs0 < 0 ? 0 : (xs0 > 255 ? 255 : xs0);
        int ys0 = (int)e.y - aY; ys0 = ys0 < 0 ? 0 : (ys0 > 255 ? 255 : ys0);
        int xs1 = (int)e.z - aX; xs1 = xs1 < 0 ? 0 : (xs1 > 255 ? 255 : xs1);
        int ys1 = (int)e.w - aY; ys1 = ys1 < 0 ? 0 : (ys1 > 255 ? 255 : ys1);
        int iv0 = (xs0 >> 1) | ((ys0 >> 1) << 7);
        int iv1 = (xs1 >> 1) | ((ys1 >> 1) << 7);
        atomicOr(&sm[iv0 >> 5], 1u << (iv0 & 31));
        atomicOr(&sm[iv1 >> 5], 1u << (iv1 & 31));
    }
    __syncthreads();
    unsigned* mo = masks + (size_t)blk * 512;
    mo[tid] = sm[tid];
    mo[tid + 256] = sm[tid + 256];
}

// ---------------- outlier helpers ------------------------------------------
__device__ inline float median10(const float* v) {
    float w[10];
    #pragma unroll
    for (int i = 0; i < 10; i++) w[i] = v[i];
    #pragma unroll
    for (int i = 1; i < 10; i++) {
        float k = w[i]; int j = i - 1;
        while (j >= 0 && w[j] > k) { w[j + 1] = w[j]; j--; }
        w[j + 1] = k;
    }
    return 0.5f * (w[4] + w[5]);
}

__device__ inline bool outlier_flag(const float* w) {
    float med = median10(w);
    float d[10];
    #pragma unroll
    for (int i = 0; i < 10; i++) d[i] = fabsf(w[i] - med);
    float d0 = d[0];
    float mad = median10(d);
    return (0.6745f * d0 / mad) > 2.0f;
}

// ---------------- Kernel 3b: serial decision walk (1 wave / batch) ---------
__device__ inline unsigned wave_sum_u32(unsigned v) {
    for (int off = 32; off; off >>= 1) v += __shfl_xor(v, off);
    return v;
}

__global__ __launch_bounds__(64) void decide_kernel(const unsigned* __restrict__ masks,
                                                    const float* __restrict__ m_all,
                                                    unsigned long long* __restrict__ commitmask) {
    int b = blockIdx.x, lane = threadIdx.x;
    // outlier flags (lanes 0..33), both axes
    bool f = false;
    if (lane < N_ITER) {
        const float* mx = m_all + b * 2 * NS;
        const float* my = mx + NS;
        f = outlier_flag(&mx[S_IDX + 1 + lane]) || outlier_flag(&my[S_IDX + 1 + lane]);
    }
    unsigned long long omask = __ballot(f);
    const unsigned* mb = masks + (size_t)b * NCH * 512;
    // ver: 8 words/lane (word index = lane*8+j), loaded as 2x uint4
    uint4 v0 = ((const uint4*)mb)[lane * 2];
    uint4 v1 = ((const uint4*)mb)[lane * 2 + 1];
    unsigned ver[8] = {v0.x, v0.y, v0.z, v0.w, v1.x, v1.y, v1.z, v1.w};
    unsigned pc = 0;
    #pragma unroll
    for (int j = 0; j < 8; j++) pc += __popc(ver[j]);
    unsigned cnt = wave_sum_u32(pc);
    unsigned long long cm = 1ull;          // chunk S_IDX always committed
    for (int si = S_IDX + 1; si < E_IDX; ++si) {
        int idx = si - S_IDX;
        const uint4* dp = (const uint4*)(mb + (size_t)idx * 512);
        uint4 d0 = dp[lane * 2], d1 = dp[lane * 2 + 1];
        unsigned del[8] = {d0.x, d0.y, d0.z, d0.w, d1.x, d1.y, d1.z, d1.w};
        unsigned nl = 0;
        #pragma unroll
        for (int j = 0; j < 8; j++) nl += __popc(del[j] & ~ver[j]);
        unsigned ni = wave_sum_u32(nl);
        bool is_o = (omask >> (si - S_IDX - 1)) & 1;
        if (!is_o) {
            unsigned cn = cnt + ni;
            float ratio = (float)ni / (float)cn;   // exact ints in f32 div — matches jax
            if (ratio < 0.1f) break;               // stopped: nothing further commits
            cm |= 1ull << idx;
            cnt = cn;
            #pragma unroll
            for (int j = 0; j < 8; j++) ver[j] |= del[j];
        }
    }
    if (lane == 0) commitmask[b] = cm;
}

// ---------------- Kernel 3c: commit container for committed chunks ---------
__global__ __launch_bounds__(256) void commit_kernel(const float* __restrict__ events,
                                                     const int* __restrict__ alignedX,
                                                     const int* __restrict__ alignedY,
                                                     const unsigned long long* __restrict__ commitmask,
                                                     unsigned* __restrict__ container) {
    int blk = blockIdx.x, tid = threadIdx.x;
    int b = blk / NCH, ci = blk % NCH;
    if (!((commitmask[b] >> ci) & 1ull)) return;
    int si = S_IDX + ci;
    int aX = alignedX[b * NS + si], aY = alignedY[b * NS + si];
    unsigned* cont = container + (size_t)b * 65536;
    const float4* ev = (const float4*)(events + ((size_t)b * NEV + (size_t)si * SEG) * 2);
    for (int i = tid; i < SEG / 2; i += 256) {
        float4 e = ev[i];
        int xs0 = (int)e.x - aX; xs0 = xs0 < 0 ? 0 : (xs0 > 255 ? 255 : xs0);
        int ys0 = (int)e.y - aY; ys0 = ys0 < 0 ? 0 : (ys0 > 255 ? 255 : ys0);
        int xs1 = (int)e.z - aX; xs1 = xs1 < 0 ? 0 : (xs1 > 255 ? 255 : xs1);
        int ys1 = (int)e.w - aY; ys1 = ys1 < 0 ? 0 : (ys1 > 255 ? 255 : ys1);
        atomicAdd(&cont[xs0 | (ys0 << 8)], 1u);
        atomicAdd(&cont[xs1 | (ys1 << 8)], 1u);
    }
}

// ---------------- Kernel 4a: per-batch cv ----------------------------------
__global__ __launch_bounds__(256) void cv_kernel(const unsigned* __restrict__ container,
                                                 float* __restrict__ cvb) {
    __shared__ double sredA[4], sredB[4];
    int tid = threadIdx.x, b = blockIdx.x;
    const uint4* c4 = (const uint4*)(container + (size_t)b * 65536);
    double s = 0.0, s2 = 0.0;
    for (int i = tid; i < 16384; i += 256) {
        uint4 v = c4[i];
        double a0 = v.x, a1 = v.y, a2 = v.z, a3 = v.w;
        s += a0 + a1 + a2 + a3;
        s2 += a0 * a0 + a1 * a1 + a2 * a2 + a3 * a3;
    }
    for (int off = 32; off; off >>= 1) { s += __shfl_down(s, off); s2 += __shfl_down(s2, off); }
    if ((tid & 63) == 0) { sredA[tid >> 6] = s; sredB[tid >> 6] = s2; }
    __syncthreads();
    if (tid == 0) {
        double ts = sredA[0] + sredA[1] + sredA[2] + sredA[3];
        double ts2 = sredB[0] + sredB[1] + sredB[2] + sredB[3];
        double mean = ts / 65536.0;
        double var = (ts2 - ts * ts / 65536.0) / 65535.0;
        cvb[b] = (float)(mean + 3.0 * sqrt(var));
    }
}

// ---------------- Kernel 4b: clip/normalize --------------------------------
__global__ __launch_bounds__(256) void finish_kernel(const unsigned* __restrict__ container,
                                                     const float* __restrict__ cvb,
                                                     float* __restrict__ out) {
    int g = blockIdx.x * 256 + threadIdx.x;        // vec4 index, 262144 total
    int b = g >> 14;                               // 16384 vec4 per batch
    float cv = cvb[b];
    uint4 v = ((const uint4*)container)[g];
    float4 o;
    o.x = fminf((float)v.x, cv) / cv;
    o.y = fminf((float)v.y, cv) / cv;
    o.z = fminf((float)v.z, cv) / cv;
    o.w = fminf((float)v.w, cv) / cv;
    ((float4*)out)[g] = o;
}

// ---------------- Launcher -------------------------------------------------
extern "C" void kernel_launch(void* const* d_in, const int* in_sizes, int n_in,
                              void* d_out, int out_size, void* d_ws, size_t ws_size,
                              hipStream_t stream) {
    const float* events = (const float*)d_in[0];
    float* out = (float*)d_out;
    char* ws = (char*)d_ws;

    // workspace layout (bytes):
    //   alongX  [16*48*256 f32] @ 0        (786432)   dead after stats
    //   alongY  [16*48*256 f32] @ 786432   (786432)   dead after stats
    //   masks   [16*35*512 u32] @ 0        (1146880)  written after stats (reuses along)
    //   container[16*65536 u32] @ 1572864  (4194304)
    //   alignedX [16*48 i32]    @ 5767168  (3072)
    //   alignedY [16*48 i32]    @ 5770240  (3072)
    //   m_all   [16*2*48 f32]   @ 5773312  (6144)
    //   commitmask [16 u64]     @ 5779456  (128)
    //   cvb     [16 f32]        @ 5779584  (64)
    float*    alongX    = (float*)(ws);
    float*    alongY    = (float*)(ws + 786432);
    unsigned* masks     = (unsigned*)(ws);
    unsigned* container = (unsigned*)(ws + 1572864);
    int*      alignedX  = (int*)(ws + 5767168);
    int*      alignedY  = (int*)(ws + 5770240);
    float*    m_all     = (float*)(ws + 5773312);
    unsigned long long* commitmask = (unsigned long long*)(ws + 5779456);
    float*    cvb       = (float*)(ws + 5779584);

    hipMemsetAsync(container, 0, (size_t)NB * 65536 * sizeof(unsigned), stream);
    hist_kernel<<<NB * NS, 256, 0, stream>>>(events, alongX, alongY);
    stats_kernel<<<NB * 2, 256, 0, stream>>>(alongX, alongY, alignedX, alignedY, m_all);
    mask_kernel<<<NB * NCH, 256, 0, stream>>>(events, alignedX, alignedY, masks);
    decide_kernel<<<NB, 64, 0, stream>>>(masks, m_all, commitmask);
    commit_kernel<<<NB * NCH, 256, 0, stream>>>(events, alignedX, alignedY, commitmask, container);
    cv_kernel<<<NB, 256, 0, stream>>>(container, cvb);
    finish_kernel<<<1024, 256, 0, stream>>>(container, cvb, out);
}

// Round 3
// 295.909 us; speedup vs baseline: 1.2701x; 1.0383x over previous
//
#include <hip/hip_runtime.h>

#define NB 16
#define NEV 960000
#define NS 48
#define SEG 20000
#define S_IDX 3
#define E_IDX 38
#define N_ITER 34
#define ND 256
#define NCH 35          // chunks S_IDX .. E_IDX-1

// ---------------- Kernel 1: histograms + compact u16 events + zero container
__global__ __launch_bounds__(256) void hist_kernel(const float* __restrict__ events,
                                                   float* __restrict__ alongX,
                                                   float* __restrict__ alongY,
                                                   unsigned* __restrict__ compact,
                                                   unsigned* __restrict__ container) {
    __shared__ unsigned hx[ND], hy[ND];
    int tid = threadIdx.x;
    int blk = blockIdx.x;
    int b = blk / NS, c = blk % NS;
    hx[tid] = 0; hy[tid] = 0;
    // fold container zeroing into this (first) kernel: 262144 uint4 over 196608 threads
    {
        uint4 z = {0u, 0u, 0u, 0u};
        for (int i = blk * 256 + tid; i < 262144; i += NB * NS * 256)
            ((uint4*)container)[i] = z;
    }
    __syncthreads();
    size_t base = (size_t)b * NEV + (size_t)c * SEG;
    const float4* ev4 = (const float4*)(events + base * 2);   // 2 events per float4
    bool wr = (c >= S_IDX && c < E_IDX);
    unsigned* dst = wr ? compact + ((size_t)b * NCH + (c - S_IDX)) * (SEG / 2) : nullptr;
    for (int k = tid; k < SEG / 2; k += 256) {
        float4 v = ev4[k];
        int x0 = (int)v.x, y0 = (int)v.y, x1 = (int)v.z, y1 = (int)v.w;
        x0 = x0 > 255 ? 255 : x0; y0 = y0 > 255 ? 255 : y0;
        x1 = x1 > 255 ? 255 : x1; y1 = y1 > 255 ? 255 : y1;
        atomicAdd(&hx[x0], 1u); atomicAdd(&hy[y0], 1u);
        atomicAdd(&hx[x1], 1u); atomicAdd(&hy[y1], 1u);
        if (wr) dst[k] = (unsigned)(x0 | (y0 << 8)) | ((unsigned)(x1 | (y1 << 8)) << 16);
    }
    __syncthreads();
    int o = (b * NS + c) * ND + tid;
    alongX[o] = (float)hx[tid];
    alongY[o] = (float)hy[tid];
}

// ---------------- Kernel 2: cv, blur-centroid m, aligned -------------------
// One block per (batch, axis); 4 waves x 12 segments, wave-local reductions.
__global__ __launch_bounds__(256) void stats_kernel(const float* __restrict__ alongX,
                                                    const float* __restrict__ alongY,
                                                    int* __restrict__ alignedX,
                                                    int* __restrict__ alignedY,
                                                    float* __restrict__ m_all) {
    __shared__ float sbuf[NS * ND];        // 48 KB
    __shared__ double sredA[4], sredB[4];
    __shared__ float scv;
    int tid = threadIdx.x;
    int b = blockIdx.x >> 1, axis = blockIdx.x & 1;
    const float* along = (axis ? alongY : alongX) + (size_t)b * NS * ND;
    for (int k = 0; k < NS; k++) sbuf[k * ND + tid] = along[k * ND + tid];
    __syncthreads();
    // cv = mean + 3*std(ddof=1) over all 48*256 raw counts
    double s = 0.0, s2 = 0.0;
    for (int k = 0; k < NS; k++) { double v = sbuf[k * ND + tid]; s += v; s2 += v * v; }
    for (int off = 32; off; off >>= 1) { s += __shfl_down(s, off); s2 += __shfl_down(s2, off); }
    if ((tid & 63) == 0) { sredA[tid >> 6] = s; sredB[tid >> 6] = s2; }
    __syncthreads();
    if (tid == 0) {
        double ts = sredA[0] + sredA[1] + sredA[2] + sredA[3];
        double ts2 = sredB[0] + sredB[1] + sredB[2] + sredB[3];
        const double N = (double)(NS * ND);
        double mean = ts / N;
        double var  = (ts2 - ts * ts / N) / (N - 1.0);
        scv = (float)(mean + 3.0 * sqrt(var));
    }
    __syncthreads();
    float cv = scv;
    int wave = tid >> 6, lane = tid & 63;
    // wave w handles segments w*12 .. w*12+11; no block barriers in this loop
    for (int q = 0; q < 12; ++q) {
        int sI = wave * 12 + q;
        double acc = 0.0;
        #pragma unroll
        for (int k = 0; k < 4; ++k) {
            int d = lane + 64 * k;
            int lo = d - 2 < 0 ? 0 : d - 2;
            int hi = d + 2 > 255 ? 255 : d + 2;
            double Wd = 0.5 * (double)(lo + hi) * (double)(hi - lo + 1);
            double t = 0.0;
            #pragma unroll
            for (int ds = -2; ds <= 2; ++ds) {
                int ss = sI + ds;
                if (ss >= 0 && ss < NS) t += (double)fminf(sbuf[ss * ND + d], cv);
            }
            acc += t * Wd;
        }
        for (int off = 32; off; off >>= 1) acc += __shfl_down(acc, off);
        if (lane == 0) {
            float mf = (float)(acc * 0.04 / (double)SEG);
            m_all[(b * 2 + axis) * NS + sI] = mf;
            // m - start - (128 - start) == m - 128 (Sterbenz-exact)
            (axis ? alignedY : alignedX)[b * NS + sI] = (int)rintf(mf - 128.0f);
        }
    }
}

// ---------------- Kernel 3a: per-(batch,chunk) half-res visit masks --------
__global__ __launch_bounds__(256) void mask_kernel(const unsigned* __restrict__ compact,
                                                   const int* __restrict__ alignedX,
                                                   const int* __restrict__ alignedY,
                                                   unsigned* __restrict__ masks) {
    __shared__ unsigned sm[512];
    int tid = threadIdx.x, blk = blockIdx.x;
    int b = blk / NCH, ci = blk % NCH, si = S_IDX + ci;
    sm[tid] = 0; sm[tid + 256] = 0;
    __syncthreads();
    int aX = alignedX[b * NS + si], aY = alignedY[b * NS + si];
    const uint4* cp = (const uint4*)(compact + ((size_t)b * NCH + ci) * (SEG / 2));
    for (int i = tid; i < SEG / 8; i += 256) {     // 2500 uint4, 8 events each
        uint4 w = cp[i];
        unsigned ws[4] = {w.x, w.y, w.z, w.w};
        #pragma unroll
        for (int j = 0; j < 4; j++) {
            unsigned v = ws[j];
            #pragma unroll
            for (int h = 0; h < 2; h++) {
                unsigned e = (h ? (v >> 16) : v) & 0xFFFFu;
                int xs = (int)(e & 255u) - aX; xs = xs < 0 ? 0 : (xs > 255 ? 255 : xs);
                int ys = (int)(e >> 8)   - aY; ys = ys < 0 ? 0 : (ys > 255 ? 255 : ys);
                int iv = (xs >> 1) | ((ys >> 1) << 7);
                atomicOr(&sm[iv >> 5], 1u << (iv & 31));
            }
        }
    }
    __syncthreads();
    unsigned* mo = masks + (size_t)blk * 512;
    mo[tid] = sm[tid];
    mo[tid + 256] = sm[tid + 256];
}

// ---------------- outlier helpers ------------------------------------------
__device__ inline float median10(const float* v) {
    float w[10];
    #pragma unroll
    for (int i = 0; i < 10; i++) w[i] = v[i];
    #pragma unroll
    for (int i = 1; i < 10; i++) {
        float k = w[i]; int j = i - 1;
        while (j >= 0 && w[j] > k) { w[j + 1] = w[j]; j--; }
        w[j + 1] = k;
    }
    return 0.5f * (w[4] + w[5]);
}

__device__ inline bool outlier_flag(const float* w) {
    float med = median10(w);
    float d[10];
    #pragma unroll
    for (int i = 0; i < 10; i++) d[i] = fabsf(w[i] - med);
    float d0 = d[0];
    float mad = median10(d);
    return (0.6745f * d0 / mad) > 2.0f;
}

// ---------------- Kernel 3b: serial decision walk (1 wave / batch) ---------
__device__ inline unsigned wave_sum_u32(unsigned v) {
    for (int off = 32; off; off >>= 1) v += __shfl_xor(v, off);
    return v;
}

__global__ __launch_bounds__(64) void decide_kernel(const unsigned* __restrict__ masks,
                                                    const float* __restrict__ m_all,
                                                    unsigned long long* __restrict__ commitmask) {
    int b = blockIdx.x, lane = threadIdx.x;
    // outlier flags (lanes 0..33), both axes
    bool f = false;
    if (lane < N_ITER) {
        const float* mx = m_all + b * 2 * NS;
        const float* my = mx + NS;
        f = outlier_flag(&mx[S_IDX + 1 + lane]) || outlier_flag(&my[S_IDX + 1 + lane]);
    }
    unsigned long long omask = __ballot(f);
    const unsigned* mb = masks + (size_t)b * NCH * 512;
    // ver: 8 words/lane (word index = lane*8+j), loaded as 2x uint4
    uint4 v0 = ((const uint4*)mb)[lane * 2];
    uint4 v1 = ((const uint4*)mb)[lane * 2 + 1];
    unsigned ver[8] = {v0.x, v0.y, v0.z, v0.w, v1.x, v1.y, v1.z, v1.w};
    unsigned pc = 0;
    #pragma unroll
    for (int j = 0; j < 8; j++) pc += __popc(ver[j]);
    unsigned cnt = wave_sum_u32(pc);
    unsigned long long cm = 1ull;          // chunk S_IDX always committed
    for (int si = S_IDX + 1; si < E_IDX; ++si) {
        int idx = si - S_IDX;
        const uint4* dp = (const uint4*)(mb + (size_t)idx * 512);
        uint4 d0 = dp[lane * 2], d1 = dp[lane * 2 + 1];
        unsigned del[8] = {d0.x, d0.y, d0.z, d0.w, d1.x, d1.y, d1.z, d1.w};
        unsigned nl = 0;
        #pragma unroll
        for (int j = 0; j < 8; j++) nl += __popc(del[j] & ~ver[j]);
        unsigned ni = wave_sum_u32(nl);
        bool is_o = (omask >> (si - S_IDX - 1)) & 1;
        if (!is_o) {
            unsigned cn = cnt + ni;
            float ratio = (float)ni / (float)cn;   // exact ints in f32 div — matches jax
            if (ratio < 0.1f) break;               // stopped: nothing further commits
            cm |= 1ull << idx;
            cnt = cn;
            #pragma unroll
            for (int j = 0; j < 8; j++) ver[j] |= del[j];
        }
    }
    if (lane == 0) commitmask[b] = cm;
}

// ---------------- Kernel 3c: commit container for committed chunks ---------
__global__ __launch_bounds__(256) void commit_kernel(const unsigned* __restrict__ compact,
                                                     const unsigned long long* __restrict__ commitmask,
                                                     unsigned* __restrict__ container) {
    int blk = blockIdx.x, tid = threadIdx.x;
    int b = blk / NCH, ci = blk % NCH;
    if (!((commitmask[b] >> ci) & 1ull)) return;
    int si = S_IDX + ci;
    // aligned shifts already folded into compact? No — compact holds raw coords;
    // shifts come from aligned arrays via mask/commit symmetry. Recompute here:
    // (kept identical to mask_kernel's index math)
    // aX/aY loaded below via the aligned arrays passed through container? — we
    // pass them in compact's sibling arrays; see launcher (extra params).
    // NOTE: parameters appended:
    (void)si;
    // placeholder; real body in commit_kernel2
}

// real commit kernel (with aligned params)
__global__ __launch_bounds__(256) void commit2_kernel(const unsigned* __restrict__ compact,
                                                      const int* __restrict__ alignedX,
                                                      const int* __restrict__ alignedY,
                                                      const unsigned long long* __restrict__ commitmask,
                                                      unsigned* __restrict__ container) {
    int blk = blockIdx.x, tid = threadIdx.x;
    int b = blk / NCH, ci = blk % NCH;
    if (!((commitmask[b] >> ci) & 1ull)) return;
    int si = S_IDX + ci;
    int aX = alignedX[b * NS + si], aY = alignedY[b * NS + si];
    unsigned* cont = container + (size_t)b * 65536;
    const uint4* cp = (const uint4*)(compact + ((size_t)b * NCH + ci) * (SEG / 2));
    for (int i = tid; i < SEG / 8; i += 256) {
        uint4 w = cp[i];
        unsigned ws[4] = {w.x, w.y, w.z, w.w};
        #pragma unroll
        for (int j = 0; j < 4; j++) {
            unsigned v = ws[j];
            #pragma unroll
            for (int h = 0; h < 2; h++) {
                unsigned e = (h ? (v >> 16) : v) & 0xFFFFu;
                int xs = (int)(e & 255u) - aX; xs = xs < 0 ? 0 : (xs > 255 ? 255 : xs);
                int ys = (int)(e >> 8)   - aY; ys = ys < 0 ? 0 : (ys > 255 ? 255 : ys);
                atomicAdd(&cont[xs | (ys << 8)], 1u);
            }
        }
    }
}

// ---------------- Kernel 4a: per-batch cv ----------------------------------
__global__ __launch_bounds__(256) void cv_kernel(const unsigned* __restrict__ container,
                                                 float* __restrict__ cvb) {
    __shared__ double sredA[4], sredB[4];
    int tid = threadIdx.x, b = blockIdx.x;
    const uint4* c4 = (const uint4*)(container + (size_t)b * 65536);
    double s = 0.0, s2 = 0.0;
    for (int i = tid; i < 16384; i += 256) {
        uint4 v = c4[i];
        double a0 = v.x, a1 = v.y, a2 = v.z, a3 = v.w;
        s += a0 + a1 + a2 + a3;
        s2 += a0 * a0 + a1 * a1 + a2 * a2 + a3 * a3;
    }
    for (int off = 32; off; off >>= 1) { s += __shfl_down(s, off); s2 += __shfl_down(s2, off); }
    if ((tid & 63) == 0) { sredA[tid >> 6] = s; sredB[tid >> 6] = s2; }
    __syncthreads();
    if (tid == 0) {
        double ts = sredA[0] + sredA[1] + sredA[2] + sredA[3];
        double ts2 = sredB[0] + sredB[1] + sredB[2] + sredB[3];
        double mean = ts / 65536.0;
        double var = (ts2 - ts * ts / 65536.0) / 65535.0;
        cvb[b] = (float)(mean + 3.0 * sqrt(var));
    }
}

// ---------------- Kernel 4b: clip/normalize --------------------------------
__global__ __launch_bounds__(256) void finish_kernel(const unsigned* __restrict__ container,
                                                     const float* __restrict__ cvb,
                                                     float* __restrict__ out) {
    int g = blockIdx.x * 256 + threadIdx.x;        // vec4 index, 262144 total
    int b = g >> 14;                               // 16384 vec4 per batch
    float cv = cvb[b];
    uint4 v = ((const uint4*)container)[g];
    float4 o;
    o.x = fminf((float)v.x, cv) / cv;
    o.y = fminf((float)v.y, cv) / cv;
    o.z = fminf((float)v.z, cv) / cv;
    o.w = fminf((float)v.w, cv) / cv;
    ((float4*)out)[g] = o;
}

// ---------------- Launcher -------------------------------------------------
extern "C" void kernel_launch(void* const* d_in, const int* in_sizes, int n_in,
                              void* d_out, int out_size, void* d_ws, size_t ws_size,
                              hipStream_t stream) {
    const float* events = (const float*)d_in[0];
    float* out = (float*)d_out;
    char* ws = (char*)d_ws;

    // workspace layout (bytes):
    //   alongX  [16*48*256 f32] @ 0        (786432)
    //   alongY  [16*48*256 f32] @ 786432   (786432)
    //   container[16*65536 u32] @ 1572864  (4194304)
    //   alignedX [16*48 i32]    @ 5767168  (3072)
    //   alignedY [16*48 i32]    @ 5770240  (3072)
    //   m_all   [16*2*48 f32]   @ 5773312  (6144)
    //   commitmask [16 u64]     @ 5779456  (128)
    //   cvb     [16 f32]        @ 5779584  (64)
    //   compact [16*35*10000 u32] @ 6291456 (22400000)
    //   masks   [16*35*512 u32] @ 29360128 (1146880)
    float*    alongX    = (float*)(ws);
    float*    alongY    = (float*)(ws + 786432);
    unsigned* container = (unsigned*)(ws + 1572864);
    int*      alignedX  = (int*)(ws + 5767168);
    int*      alignedY  = (int*)(ws + 5770240);
    float*    m_all     = (float*)(ws + 5773312);
    unsigned long long* commitmask = (unsigned long long*)(ws + 5779456);
    float*    cvb       = (float*)(ws + 5779584);
    unsigned* compact   = (unsigned*)(ws + 6291456);
    unsigned* masks     = (unsigned*)(ws + 29360128);

    hist_kernel<<<NB * NS, 256, 0, stream>>>(events, alongX, alongY, compact, container);
    stats_kernel<<<NB * 2, 256, 0, stream>>>(alongX, alongY, alignedX, alignedY, m_all);
    mask_kernel<<<NB * NCH, 256, 0, stream>>>(compact, alignedX, alignedY, masks);
    decide_kernel<<<NB, 64, 0, stream>>>(masks, m_all, commitmask);
    commit2_kernel<<<NB * NCH, 256, 0, stream>>>(compact, alignedX, alignedY, commitmask, container);
    cv_kernel<<<NB, 256, 0, stream>>>(container, cvb);
    finish_kernel<<<1024, 256, 0, stream>>>(container, cvb, out);
}

// Round 4
// 280.825 us; speedup vs baseline: 1.3383x; 1.0537x over previous
//
#include <hip/hip_runtime.h>

#define NB 16
#define NEV 960000
#define NS 48
#define SEG 20000
#define S_IDX 3
#define E_IDX 38
#define N_ITER 34
#define ND 256
#define NCH 35          // chunks S_IDX .. E_IDX-1

// ---------------- Kernel 1: histograms + compact u16 events + zero container
__global__ __launch_bounds__(256) void hist_kernel(const float* __restrict__ events,
                                                   float* __restrict__ alongX,
                                                   float* __restrict__ alongY,
                                                   unsigned* __restrict__ compact,
                                                   unsigned* __restrict__ container,
                                                   unsigned long long* __restrict__ sums) {
    __shared__ unsigned hx[ND], hy[ND];
    int tid = threadIdx.x;
    int blk = blockIdx.x;
    int b = blk / NS, c = blk % NS;
    hx[tid] = 0; hy[tid] = 0;
    // fold zeroing into this (first) kernel: container (4 MB) + cv accumulators
    {
        uint4 z = {0u, 0u, 0u, 0u};
        for (int i = blk * 256 + tid; i < 262144; i += NB * NS * 256)
            ((uint4*)container)[i] = z;
        if (blk == 0 && tid < NB * 2) sums[tid] = 0ull;
    }
    __syncthreads();
    size_t base = (size_t)b * NEV + (size_t)c * SEG;
    const float4* ev4 = (const float4*)(events + base * 2);   // 2 events per float4
    bool wr = (c >= S_IDX && c < E_IDX);
    unsigned* dst = wr ? compact + ((size_t)b * NCH + (c - S_IDX)) * (SEG / 2) : nullptr;
    for (int k = tid; k < SEG / 2; k += 256) {
        float4 v = ev4[k];
        int x0 = (int)v.x, y0 = (int)v.y, x1 = (int)v.z, y1 = (int)v.w;
        x0 = x0 > 255 ? 255 : x0; y0 = y0 > 255 ? 255 : y0;
        x1 = x1 > 255 ? 255 : x1; y1 = y1 > 255 ? 255 : y1;
        atomicAdd(&hx[x0], 1u); atomicAdd(&hy[y0], 1u);
        atomicAdd(&hx[x1], 1u); atomicAdd(&hy[y1], 1u);
        if (wr) dst[k] = (unsigned)(x0 | (y0 << 8)) | ((unsigned)(x1 | (y1 << 8)) << 16);
    }
    __syncthreads();
    int o = (b * NS + c) * ND + tid;
    alongX[o] = (float)hx[tid];
    alongY[o] = (float)hy[tid];
}

// ---------------- Kernel 2: cv, blur-centroid m, aligned -------------------
// One block per (batch, axis); 4 waves x 12 segments, wave-local reductions.
__global__ __launch_bounds__(256) void stats_kernel(const float* __restrict__ alongX,
                                                    const float* __restrict__ alongY,
                                                    int* __restrict__ alignedX,
                                                    int* __restrict__ alignedY,
                                                    float* __restrict__ m_all) {
    __shared__ float sbuf[NS * ND];        // 48 KB
    __shared__ double sredA[4], sredB[4];
    __shared__ float scv;
    int tid = threadIdx.x;
    int b = blockIdx.x >> 1, axis = blockIdx.x & 1;
    const float* along = (axis ? alongY : alongX) + (size_t)b * NS * ND;
    for (int k = 0; k < NS; k++) sbuf[k * ND + tid] = along[k * ND + tid];
    __syncthreads();
    // cv = mean + 3*std(ddof=1) over all 48*256 raw counts
    double s = 0.0, s2 = 0.0;
    for (int k = 0; k < NS; k++) { double v = sbuf[k * ND + tid]; s += v; s2 += v * v; }
    for (int off = 32; off; off >>= 1) { s += __shfl_down(s, off); s2 += __shfl_down(s2, off); }
    if ((tid & 63) == 0) { sredA[tid >> 6] = s; sredB[tid >> 6] = s2; }
    __syncthreads();
    if (tid == 0) {
        double ts = sredA[0] + sredA[1] + sredA[2] + sredA[3];
        double ts2 = sredB[0] + sredB[1] + sredB[2] + sredB[3];
        const double N = (double)(NS * ND);
        double mean = ts / N;
        double var  = (ts2 - ts * ts / N) / (N - 1.0);
        scv = (float)(mean + 3.0 * sqrt(var));
    }
    __syncthreads();
    float cv = scv;
    int wave = tid >> 6, lane = tid & 63;
    // wave w handles segments w*12 .. w*12+11; no block barriers in this loop
    for (int q = 0; q < 12; ++q) {
        int sI = wave * 12 + q;
        double acc = 0.0;
        #pragma unroll
        for (int k = 0; k < 4; ++k) {
            int d = lane + 64 * k;
            int lo = d - 2 < 0 ? 0 : d - 2;
            int hi = d + 2 > 255 ? 255 : d + 2;
            double Wd = 0.5 * (double)(lo + hi) * (double)(hi - lo + 1);
            double t = 0.0;
            #pragma unroll
            for (int ds = -2; ds <= 2; ++ds) {
                int ss = sI + ds;
                if (ss >= 0 && ss < NS) t += (double)fminf(sbuf[ss * ND + d], cv);
            }
            acc += t * Wd;
        }
        for (int off = 32; off; off >>= 1) acc += __shfl_down(acc, off);
        if (lane == 0) {
            float mf = (float)(acc * 0.04 / (double)SEG);
            m_all[(b * 2 + axis) * NS + sI] = mf;
            // m - start - (128 - start) == m - 128 (Sterbenz-exact)
            (axis ? alignedY : alignedX)[b * NS + sI] = (int)rintf(mf - 128.0f);
        }
    }
}

// ---------------- Kernel 3a: per-(batch,chunk) half-res visit masks --------
__global__ __launch_bounds__(256) void mask_kernel(const unsigned* __restrict__ compact,
                                                   const int* __restrict__ alignedX,
                                                   const int* __restrict__ alignedY,
                                                   unsigned* __restrict__ masks) {
    __shared__ unsigned sm[512];
    int tid = threadIdx.x, blk = blockIdx.x;
    int b = blk / NCH, ci = blk % NCH, si = S_IDX + ci;
    sm[tid] = 0; sm[tid + 256] = 0;
    __syncthreads();
    int aX = alignedX[b * NS + si], aY = alignedY[b * NS + si];
    const uint4* cp = (const uint4*)(compact + ((size_t)b * NCH + ci) * (SEG / 2));
    for (int i = tid; i < SEG / 8; i += 256) {     // 2500 uint4, 8 events each
        uint4 w = cp[i];
        unsigned ws[4] = {w.x, w.y, w.z, w.w};
        #pragma unroll
        for (int j = 0; j < 4; j++) {
            unsigned v = ws[j];
            #pragma unroll
            for (int h = 0; h < 2; h++) {
                unsigned e = (h ? (v >> 16) : v) & 0xFFFFu;
                int xs = (int)(e & 255u) - aX; xs = xs < 0 ? 0 : (xs > 255 ? 255 : xs);
                int ys = (int)(e >> 8)   - aY; ys = ys < 0 ? 0 : (ys > 255 ? 255 : ys);
                int iv = (xs >> 1) | ((ys >> 1) << 7);
                atomicOr(&sm[iv >> 5], 1u << (iv & 31));
            }
        }
    }
    __syncthreads();
    unsigned* mo = masks + (size_t)blk * 512;
    mo[tid] = sm[tid];
    mo[tid + 256] = sm[tid + 256];
}

// ---------------- outlier helpers ------------------------------------------
__device__ inline float median10(const float* v) {
    float w[10];
    #pragma unroll
    for (int i = 0; i < 10; i++) w[i] = v[i];
    #pragma unroll
    for (int i = 1; i < 10; i++) {
        float k = w[i]; int j = i - 1;
        while (j >= 0 && w[j] > k) { w[j + 1] = w[j]; j--; }
        w[j + 1] = k;
    }
    return 0.5f * (w[4] + w[5]);
}

__device__ inline bool outlier_flag(const float* w) {
    float med = median10(w);
    float d[10];
    #pragma unroll
    for (int i = 0; i < 10; i++) d[i] = fabsf(w[i] - med);
    float d0 = d[0];
    float mad = median10(d);
    return (0.6745f * d0 / mad) > 2.0f;
}

// ---------------- Kernel 3b: serial decision walk (1 wave / batch) ---------
__device__ inline unsigned wave_sum_u32(unsigned v) {
    for (int off = 32; off; off >>= 1) v += __shfl_xor(v, off);
    return v;
}

__global__ __launch_bounds__(64) void decide_kernel(const unsigned* __restrict__ masks,
                                                    const float* __restrict__ m_all,
                                                    unsigned long long* __restrict__ commitmask) {
    int b = blockIdx.x, lane = threadIdx.x;
    const unsigned* mb = masks + (size_t)b * NCH * 512;
    // ver: 8 words/lane (word index = lane*8+j), loaded as 2x uint4
    uint4 v0 = ((const uint4*)mb)[lane * 2];
    uint4 v1 = ((const uint4*)mb)[lane * 2 + 1];
    // prefetch chunk idx=1
    const uint4* pp = (const uint4*)(mb + 512);
    uint4 p0 = pp[lane * 2], p1 = pp[lane * 2 + 1];
    // outlier flags (lanes 0..33), both axes — computed while loads are in flight
    bool f = false;
    if (lane < N_ITER) {
        const float* mx = m_all + b * 2 * NS;
        const float* my = mx + NS;
        f = outlier_flag(&mx[S_IDX + 1 + lane]) || outlier_flag(&my[S_IDX + 1 + lane]);
    }
    unsigned long long omask = __ballot(f);
    unsigned ver[8] = {v0.x, v0.y, v0.z, v0.w, v1.x, v1.y, v1.z, v1.w};
    unsigned pc = 0;
    #pragma unroll
    for (int j = 0; j < 8; j++) pc += __popc(ver[j]);
    unsigned cnt = wave_sum_u32(pc);
    unsigned long long cm = 1ull;          // chunk S_IDX always committed
    for (int idx = 1; idx < NCH; ++idx) {
        uint4 c0 = p0, c1 = p1;
        if (idx + 1 < NCH) {               // prefetch next chunk before the reduce chain
            const uint4* np = (const uint4*)(mb + (size_t)(idx + 1) * 512);
            p0 = np[lane * 2]; p1 = np[lane * 2 + 1];
        }
        unsigned del[8] = {c0.x, c0.y, c0.z, c0.w, c1.x, c1.y, c1.z, c1.w};
        unsigned nl = 0;
        #pragma unroll
        for (int j = 0; j < 8; j++) nl += __popc(del[j] & ~ver[j]);
        unsigned ni = wave_sum_u32(nl);
        bool is_o = (omask >> (idx - 1)) & 1;
        if (!is_o) {
            unsigned cn = cnt + ni;
            float ratio = (float)ni / (float)cn;   // exact ints in f32 div — matches jax
            if (ratio < 0.1f) break;               // stopped: nothing further commits
            cm |= 1ull << idx;
            cnt = cn;
            #pragma unroll
            for (int j = 0; j < 8; j++) ver[j] |= del[j];
        }
    }
    if (lane == 0) commitmask[b] = cm;
}

// ---------------- Kernel 3c: commit container for committed chunks ---------
__global__ __launch_bounds__(256) void commit_kernel(const unsigned* __restrict__ compact,
                                                     const int* __restrict__ alignedX,
                                                     const int* __restrict__ alignedY,
                                                     const unsigned long long* __restrict__ commitmask,
                                                     unsigned* __restrict__ container) {
    int blk = blockIdx.x, tid = threadIdx.x;
    int b = blk / NCH, ci = blk % NCH;
    if (!((commitmask[b] >> ci) & 1ull)) return;
    int si = S_IDX + ci;
    int aX = alignedX[b * NS + si], aY = alignedY[b * NS + si];
    unsigned* cont = container + (size_t)b * 65536;
    const uint4* cp = (const uint4*)(compact + ((size_t)b * NCH + ci) * (SEG / 2));
    for (int i = tid; i < SEG / 8; i += 256) {
        uint4 w = cp[i];
        unsigned ws[4] = {w.x, w.y, w.z, w.w};
        #pragma unroll
        for (int j = 0; j < 4; j++) {
            unsigned v = ws[j];
            #pragma unroll
            for (int h = 0; h < 2; h++) {
                unsigned e = (h ? (v >> 16) : v) & 0xFFFFu;
                int xs = (int)(e & 255u) - aX; xs = xs < 0 ? 0 : (xs > 255 ? 255 : xs);
                int ys = (int)(e >> 8)   - aY; ys = ys < 0 ? 0 : (ys > 255 ? 255 : ys);
                atomicAdd(&cont[xs | (ys << 8)], 1u);
            }
        }
    }
}

// ---------------- Kernel 4a: per-batch cv partials (exact u64) -------------
// 16 blocks per batch; integer sums are order-independent => deterministic.
__global__ __launch_bounds__(256) void cv_kernel(const unsigned* __restrict__ container,
                                                 unsigned long long* __restrict__ sums) {
    __shared__ unsigned long long sredA[4], sredB[4];
    int tid = threadIdx.x, blk = blockIdx.x;
    int b = blk >> 4, part = blk & 15;
    const uint4* c4 = (const uint4*)(container + (size_t)b * 65536) + part * 1024;
    unsigned long long s = 0, s2 = 0;
    for (int i = tid; i < 1024; i += 256) {
        uint4 v = c4[i];
        s  += (unsigned long long)v.x + v.y + v.z + v.w;
        s2 += (unsigned long long)v.x * v.x + (unsigned long long)v.y * v.y
            + (unsigned long long)v.z * v.z + (unsigned long long)v.w * v.w;
    }
    for (int off = 32; off; off >>= 1) { s += __shfl_down(s, off); s2 += __shfl_down(s2, off); }
    if ((tid & 63) == 0) { sredA[tid >> 6] = s; sredB[tid >> 6] = s2; }
    __syncthreads();
    if (tid == 0) {
        atomicAdd(&sums[b * 2],     sredA[0] + sredA[1] + sredA[2] + sredA[3]);
        atomicAdd(&sums[b * 2 + 1], sredB[0] + sredB[1] + sredB[2] + sredB[3]);
    }
}

// ---------------- Kernel 4b: clip/normalize (cv recomputed per-thread) -----
__global__ __launch_bounds__(256) void finish_kernel(const unsigned* __restrict__ container,
                                                     const unsigned long long* __restrict__ sums,
                                                     float* __restrict__ out) {
    int g = blockIdx.x * 256 + threadIdx.x;        // vec4 index, 262144 total
    int b = g >> 14;                               // 16384 vec4 per batch
    double ts  = (double)sums[b * 2];              // exact: < 2^53
    double ts2 = (double)sums[b * 2 + 1];
    double mean = ts / 65536.0;
    double var  = (ts2 - ts * ts / 65536.0) / 65535.0;
    float cv = (float)(mean + 3.0 * sqrt(var));
    uint4 v = ((const uint4*)container)[g];
    float4 o;
    o.x = fminf((float)v.x, cv) / cv;
    o.y = fminf((float)v.y, cv) / cv;
    o.z = fminf((float)v.z, cv) / cv;
    o.w = fminf((float)v.w, cv) / cv;
    ((float4*)out)[g] = o;
}

// ---------------- Launcher -------------------------------------------------
extern "C" void kernel_launch(void* const* d_in, const int* in_sizes, int n_in,
                              void* d_out, int out_size, void* d_ws, size_t ws_size,
                              hipStream_t stream) {
    const float* events = (const float*)d_in[0];
    float* out = (float*)d_out;
    char* ws = (char*)d_ws;

    // workspace layout (bytes):
    //   alongX  [16*48*256 f32] @ 0        (786432)
    //   alongY  [16*48*256 f32] @ 786432   (786432)
    //   container[16*65536 u32] @ 1572864  (4194304)
    //   alignedX [16*48 i32]    @ 5767168  (3072)
    //   alignedY [16*48 i32]    @ 5770240  (3072)
    //   m_all   [16*2*48 f32]   @ 5773312  (6144)
    //   commitmask [16 u64]     @ 5779456  (128)
    //   sums    [16*2 u64]      @ 5779584  (256)
    //   compact [16*35*10000 u32] @ 6291456 (22400000)
    //   masks   [16*35*512 u32] @ 29360128 (1146880)
    float*    alongX    = (float*)(ws);
    float*    alongY    = (float*)(ws + 786432);
    unsigned* container = (unsigned*)(ws + 1572864);
    int*      alignedX  = (int*)(ws + 5767168);
    int*      alignedY  = (int*)(ws + 5770240);
    float*    m_all     = (float*)(ws + 5773312);
    unsigned long long* commitmask = (unsigned long long*)(ws + 5779456);
    unsigned long long* sums       = (unsigned long long*)(ws + 5779584);
    unsigned* compact   = (unsigned*)(ws + 6291456);
    unsigned* masks     = (unsigned*)(ws + 29360128);

    hist_kernel<<<NB * NS, 256, 0, stream>>>(events, alongX, alongY, compact, container, sums);
    stats_kernel<<<NB * 2, 256, 0, stream>>>(alongX, alongY, alignedX, alignedY, m_all);
    mask_kernel<<<NB * NCH, 256, 0, stream>>>(compact, alignedX, alignedY, masks);
    decide_kernel<<<NB, 64, 0, stream>>>(masks, m_all, commitmask);
    commit_kernel<<<NB * NCH, 256, 0, stream>>>(compact, alignedX, alignedY, commitmask, container);
    cv_kernel<<<NB * 16, 256, 0, stream>>>(container, sums);
    finish_kernel<<<1024, 256, 0, stream>>>(container, sums, out);
}